// Round 8
// baseline (961.636 us; speedup 1.0000x reference)
//
#include <hip/hip_runtime.h>

// ---------------------------------------------------------------------------
// GAT_L3: 3x (GATConv -> BatchNorm -> ReLU), N=50000, E=800000 (+N self-loops).
// Round 8: (1) gemm = r6 tiled structure at M=64 (782 blocks vs 391; r6 was
// grid-starved at 8% occupancy) with kc-loop unroll(1) to cap VGPR, BN+ReLU
// fused in staging (norm_relu passes deleted). (2) CSR scatter split into
// bucket-scatter (dst/64 buckets, write-combined) + sequential placement
// (r7 scatter_k burned 56MB write-through on random 4B col writes).
// ---------------------------------------------------------------------------

__device__ __forceinline__ float lrelu(float x) { return x > 0.f ? x : 0.2f * x; }
__device__ __forceinline__ unsigned short f2bf(float x) {
    unsigned u = __float_as_uint(x);
    return (unsigned short)((u + 0x7FFFu + ((u >> 16) & 1u)) >> 16);
}
__device__ __forceinline__ float bf2f(unsigned short v) {
    return __uint_as_float(((unsigned)v) << 16);
}

// ---------------------------------------------------------------------------
// Tiled GEMM + attention epilogue. Tile: M=64 nodes x OUTF, BK=32 chunks.
// Thread: 4 nodes {l16, l16+16, l16+32, l16+48} x JPT=OUTF/16 features.
// FUSE: BN scale/shift + ReLU applied during x staging.
// ---------------------------------------------------------------------------
template <int K, int OUTF, int H, bool FUSE>
__global__ __launch_bounds__(256) void gemm_attn_k(
    const float* __restrict__ in, const float* __restrict__ W,
    const float* __restrict__ scale, const float* __restrict__ shift,
    const float* __restrict__ a_src, const float* __restrict__ a_dst,
    unsigned short* __restrict__ hb, float* __restrict__ es,
    float* __restrict__ ed, int N)
{
    constexpr int BK = 32;
    constexpr int M = 64;
    constexpr int XS = BK + 4;          // 36-word stride
    constexpr int JPT = OUTF / 16;      // 4 (OUTF=64) or 2 (OUTF=32)
    constexpr int RS = 68;
    constexpr int JSH = (OUTF == 64) ? 6 : 5;
    __shared__ float xs[M * XS];
    __shared__ float wsl[OUTF * XS];
    __shared__ float redS[16 * RS];
    __shared__ float redD[16 * RS];

    const int tid = threadIdx.x;
    const int n0 = blockIdx.x * M;
    const int l16 = tid & 15;
    const int jt = (tid >> 4) * JPT;

    float acc[4][JPT];
#pragma unroll
    for (int i = 0; i < 4; ++i)
#pragma unroll
        for (int jj = 0; jj < JPT; ++jj) acc[i][jj] = 0.f;

#pragma unroll 1
    for (int kc = 0; kc < K; kc += BK) {
        // ---- stage x tile: 64 rows x 32 k ----
#pragma unroll
        for (int i = 0; i < 2; ++i) {
            int f = i * 256 + tid;
            int n = f >> 3;
            int kq = f & 7;
            int gn = n0 + n;
            if (gn >= N) gn = N - 1;
            float4 v = *(const float4*)(in + (size_t)gn * K + kc + kq * 4);
            if constexpr (FUSE) {
                float4 sc = *(const float4*)(scale + kc + kq * 4);
                float4 sh = *(const float4*)(shift + kc + kq * 4);
                v.x = fmaxf(v.x * sc.x + sh.x, 0.f);
                v.y = fmaxf(v.y * sc.y + sh.y, 0.f);
                v.z = fmaxf(v.z * sc.z + sh.z, 0.f);
                v.w = fmaxf(v.w * sc.w + sh.w, 0.f);
            }
            *(float4*)&xs[n * XS + kq * 4] = v;
        }
        // ---- stage W chunk transposed to [j][k] ----
#pragma unroll
        for (int i = 0; i < BK * OUTF / 256; ++i) {
            int g = i * 256 + tid;
            int j = g & (OUTF - 1);
            int kl = g >> JSH;
            wsl[j * XS + kl] = W[(size_t)(kc + kl) * OUTF + j];
        }
        __syncthreads();
#pragma unroll
        for (int k4 = 0; k4 < BK; k4 += 4) {
            float4 xv[4];
#pragma unroll
            for (int i = 0; i < 4; ++i)
                xv[i] = *(float4*)&xs[(l16 + 16 * i) * XS + k4];
#pragma unroll
            for (int jj = 0; jj < JPT; ++jj) {
                float4 wv = *(float4*)&wsl[(jt + jj) * XS + k4];
#pragma unroll
                for (int i = 0; i < 4; ++i)
                    acc[i][jj] += xv[i].x * wv.x + xv[i].y * wv.y
                                + xv[i].z * wv.z + xv[i].w * wv.w;
            }
        }
        __syncthreads();
    }

    // ---- epilogue: bf16 h store + attention-dot partials ----
    const int jg = tid >> 4;
#pragma unroll
    for (int i = 0; i < 4; ++i) {
        int r = l16 + 16 * i;
        int gn = n0 + r;
        float p = 0.f, q = 0.f;
#pragma unroll
        for (int jj = 0; jj < JPT; ++jj) {
            p += acc[i][jj] * a_src[jt + jj];
            q += acc[i][jj] * a_dst[jt + jj];
        }
        if (gn < N) {
            if constexpr (JPT == 4) {
                uint2 u;
                u.x = (unsigned)f2bf(acc[i][0]) | ((unsigned)f2bf(acc[i][1]) << 16);
                u.y = (unsigned)f2bf(acc[i][2]) | ((unsigned)f2bf(acc[i][3]) << 16);
                *(uint2*)(hb + (size_t)gn * OUTF + jt) = u;
            } else {
                unsigned u = (unsigned)f2bf(acc[i][0]) | ((unsigned)f2bf(acc[i][1]) << 16);
                *(unsigned*)(hb + (size_t)gn * OUTF + jt) = u;
            }
        }
        redS[jg * RS + r] = p;
        redD[jg * RS + r] = q;
    }
    __syncthreads();
    if (tid < M) {
        int gn = n0 + tid;
        if (gn < N) {
            if constexpr (OUTF == 64) {
                float e0 = 0.f, e1 = 0.f, d0 = 0.f, d1 = 0.f;
#pragma unroll
                for (int g = 0; g < 8; ++g) {
                    e0 += redS[g * RS + tid];
                    e1 += redS[(g + 8) * RS + tid];
                    d0 += redD[g * RS + tid];
                    d1 += redD[(g + 8) * RS + tid];
                }
                *(float2*)(es + (size_t)gn * 2) = make_float2(e0, e1);
                *(float2*)(ed + (size_t)gn * 2) = make_float2(d0, d1);
            } else {
                float e = 0.f, d = 0.f;
#pragma unroll
                for (int g = 0; g < 16; ++g) {
                    e += redS[g * RS + tid];
                    d += redD[g * RS + tid];
                }
                es[gn] = e;
                ed[gn] = d;
            }
        }
    }
}

// ---------------------------------------------------------------------------
// CSR build: histogram (deg + bucket) -> scans -> bucket-scatter -> placement.
// ---------------------------------------------------------------------------
__global__ __launch_bounds__(256) void histo_k(
    const int* __restrict__ ei, int* __restrict__ deg, int* __restrict__ bcnt,
    int E, int N)
{
    int e = blockIdx.x * 256 + threadIdx.x;
    int Et = E + N;
    if (e >= Et) return;
    int d = (e < E) ? ei[E + e] : e - E;
    atomicAdd(&deg[d], 1);
    atomicAdd(&bcnt[d >> 6], 1);
}

__global__ __launch_bounds__(256) void scan1_k(
    const int* __restrict__ deg, int* __restrict__ rowtmp,
    int* __restrict__ bsum, int N)
{
    __shared__ int ls[256];
    int i = blockIdx.x * 256 + threadIdx.x;
    int v = (i < N) ? deg[i] : 0;
    int x = v;
    ls[threadIdx.x] = x;
    __syncthreads();
#pragma unroll
    for (int ofs = 1; ofs < 256; ofs <<= 1) {
        int y = (threadIdx.x >= ofs) ? ls[threadIdx.x - ofs] : 0;
        __syncthreads();
        x += y;
        ls[threadIdx.x] = x;
        __syncthreads();
    }
    if (i < N) rowtmp[i] = x - v;
    if (threadIdx.x == 255) bsum[blockIdx.x] = x;
}

__global__ __launch_bounds__(256) void scan2_k(
    const int* __restrict__ bsum, int* __restrict__ boff, int nb)
{
    __shared__ int ls[256];
    int i = threadIdx.x;
    int v = (i < nb) ? bsum[i] : 0;
    int x = v;
    ls[i] = x;
    __syncthreads();
#pragma unroll
    for (int ofs = 1; ofs < 256; ofs <<= 1) {
        int y = (i >= ofs) ? ls[i - ofs] : 0;
        __syncthreads();
        x += y;
        ls[i] = x;
        __syncthreads();
    }
    if (i < nb) boff[i] = x - v;
}

__global__ __launch_bounds__(256) void scan3_k(
    const int* __restrict__ rowtmp, const int* __restrict__ boff,
    int* __restrict__ rowptr, int N, int Et)
{
    int i = blockIdx.x * 256 + threadIdx.x;
    if (i < N) rowptr[i] = rowtmp[i] + boff[blockIdx.x];
    if (i == 0) rowptr[N] = Et;
}

// 1024-thread exclusive scan for bucket offsets (nbk <= 1024)
__global__ __launch_bounds__(1024) void scanb_k(
    const int* __restrict__ bcnt, int* __restrict__ bofs, int nbk)
{
    __shared__ int ls[1024];
    int i = threadIdx.x;
    int v = (i < nbk) ? bcnt[i] : 0;
    int x = v;
    ls[i] = x;
    __syncthreads();
#pragma unroll
    for (int ofs = 1; ofs < 1024; ofs <<= 1) {
        int y = (i >= ofs) ? ls[i - ofs] : 0;
        __syncthreads();
        x += y;
        ls[i] = x;
        __syncthreads();
    }
    if (i < nbk) bofs[i] = x - v;
}

__global__ __launch_bounds__(256) void scatterA_k(
    const int* __restrict__ ei, const int* __restrict__ bofs,
    int* __restrict__ bcur, uint2* __restrict__ EB, int E, int N)
{
    int e = blockIdx.x * 256 + threadIdx.x;
    int Et = E + N;
    if (e >= Et) return;
    int s, d;
    if (e < E) { s = ei[e]; d = ei[E + e]; } else { s = e - E; d = s; }
    int b = d >> 6;
    int pos = atomicAdd(&bcur[b], 1);
    EB[bofs[b] + pos] = make_uint2((unsigned)s, (unsigned)d);
}

__global__ __launch_bounds__(256) void scatterB_k(
    const uint2* __restrict__ EB, const int* __restrict__ rowptr,
    int* __restrict__ cur, int* __restrict__ col, int Et)
{
    int i = blockIdx.x * 256 + threadIdx.x;
    if (i >= Et) return;
    uint2 q = EB[i];
    int pos = atomicAdd(&cur[q.y], 1);
    col[rowptr[q.y] + pos] = (int)q.x;
}

// ---------------------------------------------------------------------------
// Node softmax, no max pass (logits O(4): exp safe). Output per-edge slots:
//   H==2: uint2 {src, bf16(a0) | bf16(a1)<<16}    H==1: float2 {src_bits, a}
// ---------------------------------------------------------------------------
template <int H>
__global__ __launch_bounds__(256) void node_softmax_k(
    const int* __restrict__ rowptr, const int* __restrict__ col,
    const float* __restrict__ es, const float* __restrict__ ed,
    uint2* __restrict__ pkh, float2* __restrict__ pk2, int N)
{
    constexpr int F = H * 32;
    int t = blockIdx.x * 256 + threadIdx.x;
    int node = t / F;
    int lane = t - node * F;
    if (node >= N) return;
    int base = rowptr[node];
    int deg = rowptr[node + 1] - base;

    float ed0 = ed[node * H + 0];
    float ed1 = (H == 2) ? ed[node * H + 1] : 0.f;
    const float2* es2 = (const float2*)es;

    bool have = lane < deg;
    int sc_ = 0;
    float e0c = 0.f, e1c = 0.f;
    if (have) {
        sc_ = col[base + lane];
        if (H == 2) {
            float2 v = es2[sc_];
            e0c = __expf(lrelu(v.x + ed0));
            e1c = __expf(lrelu(v.y + ed1));
        } else {
            e0c = __expf(lrelu(es[sc_] + ed0));
        }
    }
    float s0 = e0c, s1 = e1c;
    for (int e = lane + F; e < deg; e += F) {
        int s = col[base + e];
        if (H == 2) {
            float2 v = es2[s];
            s0 += __expf(lrelu(v.x + ed0));
            s1 += __expf(lrelu(v.y + ed1));
        } else {
            s0 += __expf(lrelu(es[s] + ed0));
        }
    }
#pragma unroll
    for (int m = F / 2; m; m >>= 1) {
        s0 += __shfl_xor(s0, m, F);
        if (H == 2) s1 += __shfl_xor(s1, m, F);
    }
    float rd0 = 1.f / (s0 + 1e-16f);
    float rd1 = (H == 2) ? 1.f / (s1 + 1e-16f) : 0.f;

    if (have) {
        if (H == 2)
            pkh[base + lane] = make_uint2((unsigned)sc_,
                (unsigned)f2bf(e0c * rd0) | ((unsigned)f2bf(e1c * rd1) << 16));
        else
            pk2[base + lane] = make_float2(__int_as_float(sc_), e0c * rd0);
    }
    for (int e = lane + F; e < deg; e += F) {
        int s = col[base + e];
        if (H == 2) {
            float2 v = es2[s];
            pkh[base + e] = make_uint2((unsigned)s,
                (unsigned)f2bf(__expf(lrelu(v.x + ed0)) * rd0)
              | ((unsigned)f2bf(__expf(lrelu(v.y + ed1)) * rd1) << 16));
        } else {
            pk2[base + e] = make_float2(__int_as_float(s),
                                        __expf(lrelu(es[s] + ed0)) * rd0);
        }
    }
}

// ---------------------------------------------------------------------------
// Gather (bf16 h): lane owns feature pair (2l, 2l+1). H==2: 32 lanes/node;
// H==1: 16 lanes/node. Unroll 8 -> 16 loads in flight per round trip.
// ---------------------------------------------------------------------------
template <int H>
__global__ __launch_bounds__(256) void node_gather_k(
    const int* __restrict__ rowptr, const uint2* __restrict__ pkh,
    const float2* __restrict__ pk2, const unsigned short* __restrict__ hb,
    float* __restrict__ out, int N)
{
    constexpr int F = H * 32;
    constexpr int LPN = F / 2;             // lanes per node
    int t = blockIdx.x * 256 + threadIdx.x;
    int node = t / LPN;
    int lane = t - node * LPN;
    if (node >= N) return;
    int base = rowptr[node];
    int deg = rowptr[node + 1] - base;

    const uint* h2 = (const uint*)hb;      // one uint = 2 bf16 features
    float acc0 = 0.f, acc1 = 0.f;
    int e = 0;
    if (H == 2) {
        bool hi = lane >= 16;
        const uint2* p = pkh + base;
        for (; e + 8 <= deg; e += 8) {
            uint v[8];
            float a[8];
#pragma unroll
            for (int u = 0; u < 8; ++u) {
                uint2 q = p[e + u];
                v[u] = h2[(size_t)q.x * LPN + lane];
                a[u] = bf2f((unsigned short)(hi ? (q.y >> 16) : (q.y & 0xFFFFu)));
            }
#pragma unroll
            for (int u = 0; u < 8; ++u) {
                acc0 += a[u] * bf2f((unsigned short)v[u]);
                acc1 += a[u] * bf2f((unsigned short)(v[u] >> 16));
            }
        }
        for (; e < deg; ++e) {
            uint2 q = p[e];
            uint v = h2[(size_t)q.x * LPN + lane];
            float a = bf2f((unsigned short)(hi ? (q.y >> 16) : (q.y & 0xFFFFu)));
            acc0 += a * bf2f((unsigned short)v);
            acc1 += a * bf2f((unsigned short)(v >> 16));
        }
    } else {
        const float2* p = pk2 + base;
        for (; e + 8 <= deg; e += 8) {
            uint v[8];
            float a[8];
#pragma unroll
            for (int u = 0; u < 8; ++u) {
                float2 q = p[e + u];
                v[u] = h2[(size_t)__float_as_int(q.x) * LPN + lane];
                a[u] = q.y;
            }
#pragma unroll
            for (int u = 0; u < 8; ++u) {
                acc0 += a[u] * bf2f((unsigned short)v[u]);
                acc1 += a[u] * bf2f((unsigned short)(v[u] >> 16));
            }
        }
        for (; e < deg; ++e) {
            float2 q = p[e];
            uint v = h2[(size_t)__float_as_int(q.x) * LPN + lane];
            acc0 += q.y * bf2f((unsigned short)v);
            acc1 += q.y * bf2f((unsigned short)(v >> 16));
        }
    }
    ((float2*)out)[(size_t)node * LPN + lane] = make_float2(acc0, acc1);
}

// ---------------------------------------------------------------------------
// BN: atomic-free two-stage stats, then scale/shift finalize.
// ---------------------------------------------------------------------------
template <int F>
__global__ __launch_bounds__(256) void bn_stats_k(
    const float* __restrict__ x, float* __restrict__ psum,
    float* __restrict__ psumsq, int N)
{
    constexpr int RG = 256 / F;
    int f = threadIdx.x & (F - 1);
    int r = threadIdx.x / F;
    float s = 0.f, s2 = 0.f;
    for (int n = blockIdx.x * RG + r; n < N; n += gridDim.x * RG) {
        float v = x[(size_t)n * F + f];
        s += v;
        s2 += v * v;
    }
    __shared__ float ls[256], ls2[256];
    ls[threadIdx.x] = s;
    ls2[threadIdx.x] = s2;
    __syncthreads();
    if (threadIdx.x < F) {
#pragma unroll
        for (int g = 1; g < RG; ++g) { s += ls[g * F + f]; s2 += ls2[g * F + f]; }
        psum[blockIdx.x * F + f] = s;
        psumsq[blockIdx.x * F + f] = s2;
    }
}

__global__ void bn_final_k(const float* __restrict__ psum,
                           const float* __restrict__ psumsq,
                           const float* __restrict__ gamma,
                           const float* __restrict__ beta,
                           float* __restrict__ scale, float* __restrict__ shift,
                           int N, int F, int NB)
{
    int f = threadIdx.x;
    if (f >= F) return;
    float s = 0.f, s2 = 0.f;
    for (int b = 0; b < NB; ++b) { s += psum[b * F + f]; s2 += psumsq[b * F + f]; }
    float inv = 1.f / (float)N;
    float mu = s * inv;
    float var = s2 * inv - mu * mu;
    var = fmaxf(var, 0.f);
    float rs = rsqrtf(var + 1e-5f);
    float sc = rs * gamma[f];
    scale[f] = sc;
    shift[f] = beta[f] - mu * sc;
}

__global__ __launch_bounds__(256) void out_final_k(
    const float* __restrict__ x, const float* __restrict__ scale,
    const float* __restrict__ shift, float* __restrict__ out, int total)
{
    int i = blockIdx.x * 256 + threadIdx.x;
    if (i >= total) return;
    int f = i & 31;
    out[i] = fmaxf(x[i] * scale[f] + shift[f], 0.f);
}

// ---------------------------------------------------------------------------

extern "C" void kernel_launch(void* const* d_in, const int* in_sizes, int n_in,
                              void* d_out, int out_size, void* d_ws,
                              size_t ws_size, hipStream_t stream)
{
    const float* x   = (const float*)d_in[0];
    const float* W1  = (const float*)d_in[1];
    const float* as1 = (const float*)d_in[2];
    const float* ad1 = (const float*)d_in[3];
    const float* g1  = (const float*)d_in[5];
    const float* be1 = (const float*)d_in[6];
    const float* W2  = (const float*)d_in[7];
    const float* as2 = (const float*)d_in[8];
    const float* ad2 = (const float*)d_in[9];
    const float* g2  = (const float*)d_in[11];
    const float* be2 = (const float*)d_in[12];
    const float* W3  = (const float*)d_in[13];
    const float* as3 = (const float*)d_in[14];
    const float* ad3 = (const float*)d_in[15];
    const float* g3  = (const float*)d_in[17];
    const float* be3 = (const float*)d_in[18];
    const int*   ei  = (const int*)d_in[19];

    const int N   = in_sizes[0] / 128;   // 50000
    const int E   = in_sizes[19] / 2;    // 800000
    const int Et  = E + N;
    const int nb  = (N + 255) / 256;
    const int NBK = (N + 63) >> 6;       // 782 buckets
    const int NBN = 128;                 // bn_stats blocks

    // Workspace layout (4-byte words).
    float* ws = (float*)d_ws;
    size_t off = 0;
    unsigned short* Hb = (unsigned short*)(ws + off); off += (size_t)N * 32; // bf16 [N,64]
    float* AGG = ws + off;  off += (size_t)N * 64;
    float* ES  = ws + off;  off += (size_t)N * 2;
    float* ED  = ws + off;  off += (size_t)N * 2;
    float* SC  = ws + off;  off += 64;
    float* SH  = ws + off;  off += 64;
    float* PS  = ws + off;  off += (size_t)NBN * 64;
    float* PS2 = ws + off;  off += (size_t)NBN * 64;
    int* deg    = (int*)(ws + off);  off += N;        // followed by bcnt (joint memset)
    int* bcnt   = (int*)(ws + off);  off += NBK;
    int* rowtmp = (int*)(ws + off);  off += N;        // reused as scatterB cursor
    int* bsum   = (int*)(ws + off);  off += 256;
    int* boff   = (int*)(ws + off);  off += 256;
    int* bofs   = (int*)(ws + off);  off += NBK;
    int* bcur   = (int*)(ws + off);  off += NBK;
    int* rowptr = (int*)(ws + off);  off += (size_t)N + 1;
    int* col    = (int*)(ws + off);  off += (size_t)Et;
    off = (off + 3) & ~(size_t)3;                      // 16B align
    uint2*  PKH = (uint2*)(ws + off);                  // Et 8B slots (H=2)
    float2* PK2 = (float2*)PKH;                        // layer-3 slots
    uint2*  EB  = PKH;                                 // CSR staging (dead before softmax)

    const int gemmBlocks   = (N + 63) / 64;
    const int n64Blocks    = (int)(((size_t)N * 64 + 255) / 256);
    const int n32Blocks    = (int)(((size_t)N * 32 + 255) / 256);
    const int g64Blocks    = (int)(((size_t)N * 32 + 255) / 256);  // LPN=32
    const int g32Blocks    = (int)(((size_t)N * 16 + 255) / 256);  // LPN=16
    const int edgeBlocks   = (Et + 255) / 256;

    // ---------------- CSR build (once per call) ----------------
    hipMemsetAsync(deg, 0, (size_t)(N + NBK) * sizeof(int), stream);   // deg + bcnt
    histo_k<<<edgeBlocks, 256, 0, stream>>>(ei, deg, bcnt, E, N);
    scan1_k<<<nb, 256, 0, stream>>>(deg, rowtmp, bsum, N);
    scan2_k<<<1, 256, 0, stream>>>(bsum, boff, nb);
    scan3_k<<<nb, 256, 0, stream>>>(rowtmp, boff, rowptr, N, Et);
    scanb_k<<<1, 1024, 0, stream>>>(bcnt, bofs, NBK);
    hipMemsetAsync(bcur, 0, (size_t)NBK * sizeof(int), stream);
    hipMemsetAsync(rowtmp, 0, (size_t)N * sizeof(int), stream);        // now cursor
    scatterA_k<<<edgeBlocks, 256, 0, stream>>>(ei, bofs, bcur, EB, E, N);
    scatterB_k<<<edgeBlocks, 256, 0, stream>>>(EB, rowptr, rowtmp, col, Et);

    // ---------------- Layer 1: 128 -> [2 x 32] ----------------
    gemm_attn_k<128, 64, 2, false><<<gemmBlocks, 256, 0, stream>>>(
        x, W1, nullptr, nullptr, as1, ad1, Hb, ES, ED, N);
    node_softmax_k<2><<<n64Blocks, 256, 0, stream>>>(rowptr, col, ES, ED, PKH, PK2, N);
    node_gather_k<2><<<g64Blocks, 256, 0, stream>>>(rowptr, PKH, PK2, Hb, AGG, N);
    bn_stats_k<64><<<NBN, 256, 0, stream>>>(AGG, PS, PS2, N);
    bn_final_k<<<1, 64, 0, stream>>>(PS, PS2, g1, be1, SC, SH, N, 64, NBN);

    // ---------------- Layer 2: 64 -> [2 x 32] ----------------
    gemm_attn_k<64, 64, 2, true><<<gemmBlocks, 256, 0, stream>>>(
        AGG, W2, SC, SH, as2, ad2, Hb, ES, ED, N);
    node_softmax_k<2><<<n64Blocks, 256, 0, stream>>>(rowptr, col, ES, ED, PKH, PK2, N);
    node_gather_k<2><<<g64Blocks, 256, 0, stream>>>(rowptr, PKH, PK2, Hb, AGG, N);
    bn_stats_k<64><<<NBN, 256, 0, stream>>>(AGG, PS, PS2, N);
    bn_final_k<<<1, 64, 0, stream>>>(PS, PS2, g2, be2, SC, SH, N, 64, NBN);

    // ---------------- Layer 3: 64 -> [1 x 32] ----------------
    gemm_attn_k<64, 32, 1, true><<<gemmBlocks, 256, 0, stream>>>(
        AGG, W3, SC, SH, as3, ad3, Hb, ES, ED, N);
    node_softmax_k<1><<<n32Blocks, 256, 0, stream>>>(rowptr, col, ES, ED, PKH, PK2, N);
    node_gather_k<1><<<g32Blocks, 256, 0, stream>>>(rowptr, PKH, PK2, Hb, AGG, N);
    bn_stats_k<32><<<NBN, 256, 0, stream>>>(AGG, PS, PS2, N);
    bn_final_k<<<1, 32, 0, stream>>>(PS, PS2, g3, be3, SC, SH, N, 32, NBN);
    out_final_k<<<n32Blocks, 256, 0, stream>>>(AGG, SC, SH, (float*)d_out, N * 32);
}

// Round 9
// 513.348 us; speedup vs baseline: 1.8733x; 1.8733x over previous
//
#include <hip/hip_runtime.h>

// ---------------------------------------------------------------------------
// GAT_L3: 3x (GATConv -> BatchNorm -> ReLU), N=50000, E=800000 (+N self-loops).
// Round 9: revert r8 regressions (bucketed scatter: 782-counter atomic
// contention, 260us; M=64 gemm: halved W reuse) to r6 gemm (M=128) + r7 CSR.
// NEW: softmax+gather fused into node_sg_k — first-LPN edges cached in
// registers, phase-2 broadcasts src/exp via wave-uniform shfl (v_readlane),
// packed-slot buffer + 3 launches eliminated.
// ---------------------------------------------------------------------------

__device__ __forceinline__ float lrelu(float x) { return x > 0.f ? x : 0.2f * x; }
__device__ __forceinline__ unsigned short f2bf(float x) {
    unsigned u = __float_as_uint(x);
    return (unsigned short)((u + 0x7FFFu + ((u >> 16) & 1u)) >> 16);
}
__device__ __forceinline__ float bf2f(unsigned short v) {
    return __uint_as_float(((unsigned)v) << 16);
}

// ---------------------------------------------------------------------------
// Tiled GEMM + attention epilogue (r6 version: M=128, conflict-free rows).
// ---------------------------------------------------------------------------
template <int K, int OUTF, int H, bool FUSE>
__global__ __launch_bounds__(256) void gemm_attn_k(
    const float* __restrict__ in, const float* __restrict__ W,
    const float* __restrict__ scale, const float* __restrict__ shift,
    const float* __restrict__ a_src, const float* __restrict__ a_dst,
    unsigned short* __restrict__ hb, float* __restrict__ es,
    float* __restrict__ ed, int N)
{
    constexpr int BK = 32;
    constexpr int M = 128;
    constexpr int XS = BK + 4;          // 36-word row stride
    constexpr int JPT = OUTF / 8;       // 8 (OUTF=64) or 4 (OUTF=32)
    __shared__ float xs[M * XS];
    __shared__ float ws[OUTF * XS];
    __shared__ float redS[8 * 132];
    __shared__ float redD[8 * 132];

    const int tid = threadIdx.x;
    const int n0 = blockIdx.x * M;

    float acc[4][JPT];
#pragma unroll
    for (int i = 0; i < 4; ++i)
#pragma unroll
        for (int jj = 0; jj < JPT; ++jj) acc[i][jj] = 0.f;

    const int lane = tid & 31;
    const int jt = (tid >> 5) * JPT;

    for (int kc = 0; kc < K; kc += BK) {
#pragma unroll
        for (int i = 0; i < 4; ++i) {
            int f = i * 256 + tid;
            int n = f >> 3;
            int kq = f & 7;
            int gn = n0 + n;
            if (gn >= N) gn = N - 1;
            float4 v = *(const float4*)(in + (size_t)gn * K + kc + kq * 4);
            if constexpr (FUSE) {
                float4 sc = *(const float4*)(scale + kc + kq * 4);
                float4 sh = *(const float4*)(shift + kc + kq * 4);
                v.x = fmaxf(v.x * sc.x + sh.x, 0.f);
                v.y = fmaxf(v.y * sc.y + sh.y, 0.f);
                v.z = fmaxf(v.z * sc.z + sh.z, 0.f);
                v.w = fmaxf(v.w * sc.w + sh.w, 0.f);
            }
            *(float4*)&xs[n * XS + kq * 4] = v;
        }
#pragma unroll
        for (int i = 0; i < BK * OUTF / 256; ++i) {
            int g = i * 256 + tid;
            int j = g % OUTF;
            int kl = g / OUTF;
            ws[j * XS + kl] = W[(size_t)(kc + kl) * OUTF + j];
        }
        __syncthreads();
#pragma unroll
        for (int k4 = 0; k4 < BK; k4 += 4) {
            float4 xv[4];
#pragma unroll
            for (int i = 0; i < 4; ++i)
                xv[i] = *(float4*)&xs[(lane + 32 * i) * XS + k4];
#pragma unroll
            for (int jj = 0; jj < JPT; ++jj) {
                float4 wv = *(float4*)&ws[(jt + jj) * XS + k4];
#pragma unroll
                for (int i = 0; i < 4; ++i)
                    acc[i][jj] += xv[i].x * wv.x + xv[i].y * wv.y
                                + xv[i].z * wv.z + xv[i].w * wv.w;
            }
        }
        __syncthreads();
    }

    const int jg = tid >> 5;
#pragma unroll
    for (int i = 0; i < 4; ++i) {
        int r = lane + 32 * i;
        int gn = n0 + r;
        float p = 0.f, q = 0.f;
#pragma unroll
        for (int jj = 0; jj < JPT; ++jj) {
            p += acc[i][jj] * a_src[jt + jj];
            q += acc[i][jj] * a_dst[jt + jj];
        }
        if (gn < N) {
            unsigned u[JPT / 2];
#pragma unroll
            for (int jj = 0; jj < JPT; jj += 2)
                u[jj / 2] = (unsigned)f2bf(acc[i][jj]) | ((unsigned)f2bf(acc[i][jj + 1]) << 16);
            if constexpr (JPT == 8)
                *(uint4*)(hb + (size_t)gn * OUTF + jt) = make_uint4(u[0], u[1], u[2], u[3]);
            else
                *(uint2*)(hb + (size_t)gn * OUTF + jt) = make_uint2(u[0], u[1]);
        }
        redS[jg * 132 + r] = p;
        redD[jg * 132 + r] = q;
    }
    __syncthreads();
    if (tid < M) {
        int gn = n0 + tid;
        if (gn < N) {
            if constexpr (OUTF == 64) {
                float e0 = redS[0 * 132 + tid] + redS[1 * 132 + tid]
                         + redS[2 * 132 + tid] + redS[3 * 132 + tid];
                float e1 = redS[4 * 132 + tid] + redS[5 * 132 + tid]
                         + redS[6 * 132 + tid] + redS[7 * 132 + tid];
                float d0 = redD[0 * 132 + tid] + redD[1 * 132 + tid]
                         + redD[2 * 132 + tid] + redD[3 * 132 + tid];
                float d1 = redD[4 * 132 + tid] + redD[5 * 132 + tid]
                         + redD[6 * 132 + tid] + redD[7 * 132 + tid];
                *(float2*)(es + (size_t)gn * 2) = make_float2(e0, e1);
                *(float2*)(ed + (size_t)gn * 2) = make_float2(d0, d1);
            } else {
                float e = 0.f, d = 0.f;
#pragma unroll
                for (int g = 0; g < 8; ++g) { e += redS[g * 132 + tid]; d += redD[g * 132 + tid]; }
                es[gn] = e;
                ed[gn] = d;
            }
        }
    }
}

// ---------------------------------------------------------------------------
// CSR build (r7 version): degree histogram -> scans -> single scatter.
// ---------------------------------------------------------------------------
__global__ __launch_bounds__(256) void deg_k(
    const int* __restrict__ ei, int* __restrict__ deg, int E, int N)
{
    int e = blockIdx.x * 256 + threadIdx.x;
    int Et = E + N;
    if (e >= Et) return;
    int d = (e < E) ? ei[E + e] : e - E;
    atomicAdd(&deg[d], 1);
}

__global__ __launch_bounds__(256) void scan1_k(
    const int* __restrict__ deg, int* __restrict__ rowtmp,
    int* __restrict__ bsum, int N)
{
    __shared__ int ls[256];
    int i = blockIdx.x * 256 + threadIdx.x;
    int v = (i < N) ? deg[i] : 0;
    int x = v;
    ls[threadIdx.x] = x;
    __syncthreads();
#pragma unroll
    for (int ofs = 1; ofs < 256; ofs <<= 1) {
        int y = (threadIdx.x >= ofs) ? ls[threadIdx.x - ofs] : 0;
        __syncthreads();
        x += y;
        ls[threadIdx.x] = x;
        __syncthreads();
    }
    if (i < N) rowtmp[i] = x - v;
    if (threadIdx.x == 255) bsum[blockIdx.x] = x;
}

__global__ __launch_bounds__(256) void scan2_k(
    const int* __restrict__ bsum, int* __restrict__ boff, int nb)
{
    __shared__ int ls[256];
    int i = threadIdx.x;
    int v = (i < nb) ? bsum[i] : 0;
    int x = v;
    ls[i] = x;
    __syncthreads();
#pragma unroll
    for (int ofs = 1; ofs < 256; ofs <<= 1) {
        int y = (i >= ofs) ? ls[i - ofs] : 0;
        __syncthreads();
        x += y;
        ls[i] = x;
        __syncthreads();
    }
    if (i < nb) boff[i] = x - v;
}

__global__ __launch_bounds__(256) void scan3_k(
    const int* __restrict__ rowtmp, const int* __restrict__ boff,
    int* __restrict__ rowptr, int N, int Et)
{
    int i = blockIdx.x * 256 + threadIdx.x;
    if (i < N) rowptr[i] = rowtmp[i] + boff[blockIdx.x];
    if (i == 0) rowptr[N] = Et;
}

__global__ __launch_bounds__(256) void scatter_k(
    const int* __restrict__ ei, const int* __restrict__ rowptr,
    int* __restrict__ cur, int* __restrict__ col, int E, int N)
{
    int e = blockIdx.x * 256 + threadIdx.x;
    int Et = E + N;
    if (e >= Et) return;
    int s, d;
    if (e < E) { s = ei[e]; d = ei[E + e]; } else { s = e - E; d = s; }
    int pos = atomicAdd(&cur[d], 1);
    col[rowptr[d] + pos] = s;
}

// ---------------------------------------------------------------------------
// Fused softmax + gather. LPN = H*16 lanes per node (feature pair per lane).
// Phase 1: lane caches edge `lane` (src + exp terms) in registers while
// accumulating the denominator over all edges (strided); width-LPN butterfly.
// Phase 2: edges [0, min(deg,LPN)) broadcast src/exp from registers via
// wave-uniform shfl (v_readlane -> scalar h-row base, coalesced 128B gather);
// rare tail (deg > LPN) recomputes from broadcast loads.
// No max-subtraction: logits are O(4), exp is safe (inputs scaled 0.1).
// ---------------------------------------------------------------------------
template <int H>
__global__ __launch_bounds__(256) void node_sg_k(
    const int* __restrict__ rowptr, const int* __restrict__ col,
    const float* __restrict__ es, const float* __restrict__ ed,
    const unsigned short* __restrict__ hb, float* __restrict__ out, int N)
{
    constexpr int LPN = H * 16;            // 32 (H=2) or 16 (H=1)
    int t = blockIdx.x * 256 + threadIdx.x;
    int node = t / LPN;
    int lane = t - node * LPN;
    if (node >= N) return;
    int base = rowptr[node];
    int deg = rowptr[node + 1] - base;

    const uint* h2 = (const uint*)hb;      // row stride = LPN uints
    const float2* es2 = (const float2*)es;

    float ed0, ed1 = 0.f;
    if constexpr (H == 2) {
        float2 e = ((const float2*)ed)[node];
        ed0 = e.x; ed1 = e.y;
    } else {
        ed0 = ed[node];
    }

    // ---- phase 1: cache first LPN edges; accumulate denominator ----
    int sc_ = 0;
    float x0 = 0.f, x1 = 0.f;
    if (lane < deg) {
        sc_ = col[base + lane];
        if constexpr (H == 2) {
            float2 v = es2[sc_];
            x0 = __expf(lrelu(v.x + ed0));
            x1 = __expf(lrelu(v.y + ed1));
        } else {
            x0 = __expf(lrelu(es[sc_] + ed0));
        }
    }
    float s0 = x0, s1 = x1;
    for (int e = lane + LPN; e < deg; e += LPN) {
        int s = col[base + e];
        if constexpr (H == 2) {
            float2 v = es2[s];
            s0 += __expf(lrelu(v.x + ed0));
            s1 += __expf(lrelu(v.y + ed1));
        } else {
            s0 += __expf(lrelu(es[s] + ed0));
        }
    }
#pragma unroll
    for (int m = LPN / 2; m; m >>= 1) {
        s0 += __shfl_xor(s0, m, LPN);
        if (H == 2) s1 += __shfl_xor(s1, m, LPN);
    }
    float rd0 = 1.f / (s0 + 1e-16f);
    float rd1 = (H == 2) ? 1.f / (s1 + 1e-16f) : 0.f;

    // ---- phase 2: weighted gather ----
    const bool hi = (H == 2) && (lane >= 16);
    float acc0 = 0.f, acc1 = 0.f;
    int dcap = deg < LPN ? deg : LPN;
    int e = 0;
    for (; e + 4 <= dcap; e += 4) {
        int sI[4];
        float a[4];
#pragma unroll
        for (int u = 0; u < 4; ++u) {
            sI[u] = __shfl(sc_, e + u, LPN);
            float a0 = __shfl(x0, e + u, LPN);
            if constexpr (H == 2) {
                float a1 = __shfl(x1, e + u, LPN);
                a[u] = hi ? a1 * rd1 : a0 * rd0;
            } else {
                a[u] = a0 * rd0;
            }
        }
        uint v[4];
#pragma unroll
        for (int u = 0; u < 4; ++u) v[u] = h2[(size_t)sI[u] * LPN + lane];
#pragma unroll
        for (int u = 0; u < 4; ++u) {
            acc0 += a[u] * bf2f((unsigned short)v[u]);
            acc1 += a[u] * bf2f((unsigned short)(v[u] >> 16));
        }
    }
    for (; e < dcap; ++e) {
        int sI = __shfl(sc_, e, LPN);
        float a0 = __shfl(x0, e, LPN);
        float a;
        if constexpr (H == 2) {
            float a1 = __shfl(x1, e, LPN);
            a = hi ? a1 * rd1 : a0 * rd0;
        } else {
            a = a0 * rd0;
        }
        uint v = h2[(size_t)sI * LPN + lane];
        acc0 += a * bf2f((unsigned short)v);
        acc1 += a * bf2f((unsigned short)(v >> 16));
    }
    for (int e2 = LPN; e2 < deg; ++e2) {       // rare tail
        int s = col[base + e2];
        float a;
        if constexpr (H == 2) {
            float2 vv = es2[s];
            a = hi ? __expf(lrelu(vv.y + ed1)) * rd1
                   : __expf(lrelu(vv.x + ed0)) * rd0;
        } else {
            a = __expf(lrelu(es[s] + ed0)) * rd0;
        }
        uint v = h2[(size_t)s * LPN + lane];
        acc0 += a * bf2f((unsigned short)v);
        acc1 += a * bf2f((unsigned short)(v >> 16));
    }
    ((float2*)out)[(size_t)node * LPN + lane] = make_float2(acc0, acc1);
}

// ---------------------------------------------------------------------------
// BN: atomic-free two-stage stats, then scale/shift finalize.
// ---------------------------------------------------------------------------
template <int F>
__global__ __launch_bounds__(256) void bn_stats_k(
    const float* __restrict__ x, float* __restrict__ psum,
    float* __restrict__ psumsq, int N)
{
    constexpr int RG = 256 / F;
    int f = threadIdx.x & (F - 1);
    int r = threadIdx.x / F;
    float s = 0.f, s2 = 0.f;
    for (int n = blockIdx.x * RG + r; n < N; n += gridDim.x * RG) {
        float v = x[(size_t)n * F + f];
        s += v;
        s2 += v * v;
    }
    __shared__ float ls[256], ls2[256];
    ls[threadIdx.x] = s;
    ls2[threadIdx.x] = s2;
    __syncthreads();
    if (threadIdx.x < F) {
#pragma unroll
        for (int g = 1; g < RG; ++g) { s += ls[g * F + f]; s2 += ls2[g * F + f]; }
        psum[blockIdx.x * F + f] = s;
        psumsq[blockIdx.x * F + f] = s2;
    }
}

__global__ void bn_final_k(const float* __restrict__ psum,
                           const float* __restrict__ psumsq,
                           const float* __restrict__ gamma,
                           const float* __restrict__ beta,
                           float* __restrict__ scale, float* __restrict__ shift,
                           int N, int F, int NB)
{
    int f = threadIdx.x;
    if (f >= F) return;
    float s = 0.f, s2 = 0.f;
    for (int b = 0; b < NB; ++b) { s += psum[b * F + f]; s2 += psumsq[b * F + f]; }
    float inv = 1.f / (float)N;
    float mu = s * inv;
    float var = s2 * inv - mu * mu;
    var = fmaxf(var, 0.f);
    float rs = rsqrtf(var + 1e-5f);
    float sc = rs * gamma[f];
    scale[f] = sc;
    shift[f] = beta[f] - mu * sc;
}

__global__ __launch_bounds__(256) void out_final_k(
    const float* __restrict__ x, const float* __restrict__ scale,
    const float* __restrict__ shift, float* __restrict__ out, int total)
{
    int i = blockIdx.x * 256 + threadIdx.x;
    if (i >= total) return;
    int f = i & 31;
    out[i] = fmaxf(x[i] * scale[f] + shift[f], 0.f);
}

// ---------------------------------------------------------------------------

extern "C" void kernel_launch(void* const* d_in, const int* in_sizes, int n_in,
                              void* d_out, int out_size, void* d_ws,
                              size_t ws_size, hipStream_t stream)
{
    const float* x   = (const float*)d_in[0];
    const float* W1  = (const float*)d_in[1];
    const float* as1 = (const float*)d_in[2];
    const float* ad1 = (const float*)d_in[3];
    const float* g1  = (const float*)d_in[5];
    const float* be1 = (const float*)d_in[6];
    const float* W2  = (const float*)d_in[7];
    const float* as2 = (const float*)d_in[8];
    const float* ad2 = (const float*)d_in[9];
    const float* g2  = (const float*)d_in[11];
    const float* be2 = (const float*)d_in[12];
    const float* W3  = (const float*)d_in[13];
    const float* as3 = (const float*)d_in[14];
    const float* ad3 = (const float*)d_in[15];
    const float* g3  = (const float*)d_in[17];
    const float* be3 = (const float*)d_in[18];
    const int*   ei  = (const int*)d_in[19];

    const int N  = in_sizes[0] / 128;   // 50000
    const int E  = in_sizes[19] / 2;    // 800000
    const int Et = E + N;
    const int nb = (N + 255) / 256;
    const int NBN = 128;                // bn_stats blocks

    // Workspace layout (4-byte words).
    float* ws = (float*)d_ws;
    size_t off = 0;
    unsigned short* Hb = (unsigned short*)(ws + off); off += (size_t)N * 32; // bf16 [N,64]
    float* AGG = ws + off;  off += (size_t)N * 64;
    float* ES  = ws + off;  off += (size_t)N * 2;
    float* ED  = ws + off;  off += (size_t)N * 2;
    float* SC  = ws + off;  off += 64;
    float* SH  = ws + off;  off += 64;
    float* PS  = ws + off;  off += (size_t)NBN * 64;
    float* PS2 = ws + off;  off += (size_t)NBN * 64;
    int* deg    = (int*)(ws + off);  off += N;        // reused as scatter cursor
    int* rowtmp = (int*)(ws + off);  off += N;
    int* bsum   = (int*)(ws + off);  off += 256;
    int* boff   = (int*)(ws + off);  off += 256;
    int* rowptr = (int*)(ws + off);  off += (size_t)N + 1;
    int* col    = (int*)(ws + off);  off += (size_t)Et;

    const int gemmBlocks = (N + 127) / 128;
    const int sg64Blocks = (int)(((size_t)N * 32 + 255) / 256);  // LPN=32
    const int sg32Blocks = (int)(((size_t)N * 16 + 255) / 256);  // LPN=16
    const int edgeBlocks = (Et + 255) / 256;
    const int n32Blocks  = (N * 32 + 255) / 256;

    // ---------------- CSR build (once per call) ----------------
    hipMemsetAsync(deg, 0, (size_t)N * sizeof(int), stream);
    deg_k<<<edgeBlocks, 256, 0, stream>>>(ei, deg, E, N);
    scan1_k<<<nb, 256, 0, stream>>>(deg, rowtmp, bsum, N);
    scan2_k<<<1, 256, 0, stream>>>(bsum, boff, nb);
    scan3_k<<<nb, 256, 0, stream>>>(rowtmp, boff, rowptr, N, Et);
    hipMemsetAsync(deg, 0, (size_t)N * sizeof(int), stream);
    scatter_k<<<edgeBlocks, 256, 0, stream>>>(ei, rowptr, deg, col, E, N);

    // ---------------- Layer 1: 128 -> [2 x 32] ----------------
    gemm_attn_k<128, 64, 2, false><<<gemmBlocks, 256, 0, stream>>>(
        x, W1, nullptr, nullptr, as1, ad1, Hb, ES, ED, N);
    node_sg_k<2><<<sg64Blocks, 256, 0, stream>>>(rowptr, col, ES, ED, Hb, AGG, N);
    bn_stats_k<64><<<NBN, 256, 0, stream>>>(AGG, PS, PS2, N);
    bn_final_k<<<1, 64, 0, stream>>>(PS, PS2, g1, be1, SC, SH, N, 64, NBN);

    // ---------------- Layer 2: 64 -> [2 x 32] ----------------
    gemm_attn_k<64, 64, 2, true><<<gemmBlocks, 256, 0, stream>>>(
        AGG, W2, SC, SH, as2, ad2, Hb, ES, ED, N);
    node_sg_k<2><<<sg64Blocks, 256, 0, stream>>>(rowptr, col, ES, ED, Hb, AGG, N);
    bn_stats_k<64><<<NBN, 256, 0, stream>>>(AGG, PS, PS2, N);
    bn_final_k<<<1, 64, 0, stream>>>(PS, PS2, g2, be2, SC, SH, N, 64, NBN);

    // ---------------- Layer 3: 64 -> [1 x 32] ----------------
    gemm_attn_k<64, 32, 1, true><<<gemmBlocks, 256, 0, stream>>>(
        AGG, W3, SC, SH, as3, ad3, Hb, ES, ED, N);
    node_sg_k<1><<<sg32Blocks, 256, 0, stream>>>(rowptr, col, ES, ED, Hb, AGG, N);
    bn_stats_k<32><<<NBN, 256, 0, stream>>>(AGG, PS, PS2, N);
    bn_final_k<<<1, 32, 0, stream>>>(PS, PS2, g3, be3, SC, SH, N, 32, NBN);
    out_final_k<<<n32Blocks, 256, 0, stream>>>(AGG, SC, SH, (float*)d_out, N * 32);
}

// Round 10
// 480.775 us; speedup vs baseline: 2.0002x; 1.0678x over previous
//
#include <hip/hip_runtime.h>

// ---------------------------------------------------------------------------
// GAT_L3: 3x (GATConv -> BatchNorm -> ReLU), N=50000, E=800000 (+N self-loops).
// Round 10: gemm grid split along heads — block = (128-node tile) x (32-feat
// head slice). r9 gemm was grid-starved (391 blocks, 9% occupancy, VGPR 172).
// Head-split keeps 128-row W reuse (disjoint W columns per head block; only
// the x-tile is staged twice), acc drops to [4][4] -> lower VGPR, 782 blocks.
// Attention dot factorizes per head, so epilogue stays block-local.
// Rest (CSR, fused node_sg, BN) identical to r9.
// ---------------------------------------------------------------------------

__device__ __forceinline__ float lrelu(float x) { return x > 0.f ? x : 0.2f * x; }
__device__ __forceinline__ unsigned short f2bf(float x) {
    unsigned u = __float_as_uint(x);
    return (unsigned short)((u + 0x7FFFu + ((u >> 16) & 1u)) >> 16);
}
__device__ __forceinline__ float bf2f(unsigned short v) {
    return __uint_as_float(((unsigned)v) << 16);
}

// ---------------------------------------------------------------------------
// Tiled GEMM + attention epilogue, head-split.
// Block: 128 nodes x 32 features (head slice hs of HS=OUTF/32).
// Thread: rows {l, l+32, l+64, l+96} (l=tid&31) x 4 features (jt=(tid>>5)*4).
// FUSE: BN scale/shift + ReLU applied during x staging.
// ---------------------------------------------------------------------------
template <int K, int OUTF, int H, bool FUSE>
__global__ __launch_bounds__(256) void gemm_attn_k(
    const float* __restrict__ in, const float* __restrict__ W,
    const float* __restrict__ scale, const float* __restrict__ shift,
    const float* __restrict__ a_src, const float* __restrict__ a_dst,
    unsigned short* __restrict__ hb, float* __restrict__ es,
    float* __restrict__ ed, int N)
{
    constexpr int BK = 32;
    constexpr int M = 128;
    constexpr int XS = BK + 4;          // 36-word row stride
    constexpr int HS = OUTF / 32;       // head slices per tile (2 or 1)
    __shared__ float xs[M * XS];
    __shared__ float ws[32 * XS];
    __shared__ float redS[8 * 132];
    __shared__ float redD[8 * 132];

    const int tid = threadIdx.x;
    const int tile = (HS == 2) ? (blockIdx.x >> 1) : blockIdx.x;
    const int hs = (HS == 2) ? (blockIdx.x & 1) : 0;
    const int n0 = tile * M;
    const int jb = hs * 32;             // global feature base of this slice

    float acc[4][4];
#pragma unroll
    for (int i = 0; i < 4; ++i)
#pragma unroll
        for (int jj = 0; jj < 4; ++jj) acc[i][jj] = 0.f;

    const int lane = tid & 31;
    const int jt = (tid >> 5) * 4;      // local feature group (0..28)

    for (int kc = 0; kc < K; kc += BK) {
        // ---- stage x tile: 128 rows x 32 k, coalesced float4 ----
#pragma unroll
        for (int i = 0; i < 4; ++i) {
            int f = i * 256 + tid;
            int n = f >> 3;
            int kq = f & 7;
            int gn = n0 + n;
            if (gn >= N) gn = N - 1;
            float4 v = *(const float4*)(in + (size_t)gn * K + kc + kq * 4);
            if constexpr (FUSE) {
                float4 sc = *(const float4*)(scale + kc + kq * 4);
                float4 sh = *(const float4*)(shift + kc + kq * 4);
                v.x = fmaxf(v.x * sc.x + sh.x, 0.f);
                v.y = fmaxf(v.y * sc.y + sh.y, 0.f);
                v.z = fmaxf(v.z * sc.z + sh.z, 0.f);
                v.w = fmaxf(v.w * sc.w + sh.w, 0.f);
            }
            *(float4*)&xs[n * XS + kq * 4] = v;
        }
        // ---- stage W slice transposed to [j_local][k] (32x32) ----
        {
            int g = tid;                // 1024 elems, 4 per thread
#pragma unroll
            for (int i = 0; i < 4; ++i, g += 256) {
                int j = g & 31;
                int kl = g >> 5;
                ws[j * XS + kl] = W[(size_t)(kc + kl) * OUTF + jb + j];
            }
        }
        __syncthreads();
#pragma unroll
        for (int k4 = 0; k4 < BK; k4 += 4) {
            float4 xv[4];
#pragma unroll
            for (int i = 0; i < 4; ++i)
                xv[i] = *(float4*)&xs[(lane + 32 * i) * XS + k4];
#pragma unroll
            for (int jj = 0; jj < 4; ++jj) {
                float4 wv = *(float4*)&ws[(jt + jj) * XS + k4];
#pragma unroll
                for (int i = 0; i < 4; ++i)
                    acc[i][jj] += xv[i].x * wv.x + xv[i].y * wv.y
                                + xv[i].z * wv.z + xv[i].w * wv.w;
            }
        }
        __syncthreads();
    }

    // ---- epilogue: bf16 h store (this slice) + head attention dots ----
    const int jg = tid >> 5;
#pragma unroll
    for (int i = 0; i < 4; ++i) {
        int r = lane + 32 * i;
        int gn = n0 + r;
        float p = 0.f, q = 0.f;
#pragma unroll
        for (int jj = 0; jj < 4; ++jj) {
            p += acc[i][jj] * a_src[jb + jt + jj];
            q += acc[i][jj] * a_dst[jb + jt + jj];
        }
        if (gn < N) {
            uint2 u;
            u.x = (unsigned)f2bf(acc[i][0]) | ((unsigned)f2bf(acc[i][1]) << 16);
            u.y = (unsigned)f2bf(acc[i][2]) | ((unsigned)f2bf(acc[i][3]) << 16);
            *(uint2*)(hb + (size_t)gn * OUTF + jb + jt) = u;
        }
        redS[jg * 132 + r] = p;
        redD[jg * 132 + r] = q;
    }
    __syncthreads();
    if (tid < M) {
        int gn = n0 + tid;
        if (gn < N) {
            float e = 0.f, d = 0.f;
#pragma unroll
            for (int g = 0; g < 8; ++g) {
                e += redS[g * 132 + tid];
                d += redD[g * 132 + tid];
            }
            es[gn * H + hs] = e;
            ed[gn * H + hs] = d;
        }
    }
}

// ---------------------------------------------------------------------------
// CSR build: degree histogram -> two-level exclusive scan -> scatter.
// ---------------------------------------------------------------------------
__global__ __launch_bounds__(256) void deg_k(
    const int* __restrict__ ei, int* __restrict__ deg, int E, int N)
{
    int e = blockIdx.x * 256 + threadIdx.x;
    int Et = E + N;
    if (e >= Et) return;
    int d = (e < E) ? ei[E + e] : e - E;
    atomicAdd(&deg[d], 1);
}

__global__ __launch_bounds__(256) void scan1_k(
    const int* __restrict__ deg, int* __restrict__ rowtmp,
    int* __restrict__ bsum, int N)
{
    __shared__ int ls[256];
    int i = blockIdx.x * 256 + threadIdx.x;
    int v = (i < N) ? deg[i] : 0;
    int x = v;
    ls[threadIdx.x] = x;
    __syncthreads();
#pragma unroll
    for (int ofs = 1; ofs < 256; ofs <<= 1) {
        int y = (threadIdx.x >= ofs) ? ls[threadIdx.x - ofs] : 0;
        __syncthreads();
        x += y;
        ls[threadIdx.x] = x;
        __syncthreads();
    }
    if (i < N) rowtmp[i] = x - v;
    if (threadIdx.x == 255) bsum[blockIdx.x] = x;
}

__global__ __launch_bounds__(256) void scan2_k(
    const int* __restrict__ bsum, int* __restrict__ boff, int nb)
{
    __shared__ int ls[256];
    int i = threadIdx.x;
    int v = (i < nb) ? bsum[i] : 0;
    int x = v;
    ls[i] = x;
    __syncthreads();
#pragma unroll
    for (int ofs = 1; ofs < 256; ofs <<= 1) {
        int y = (i >= ofs) ? ls[i - ofs] : 0;
        __syncthreads();
        x += y;
        ls[i] = x;
        __syncthreads();
    }
    if (i < nb) boff[i] = x - v;
}

__global__ __launch_bounds__(256) void scan3_k(
    const int* __restrict__ rowtmp, const int* __restrict__ boff,
    int* __restrict__ rowptr, int N, int Et)
{
    int i = blockIdx.x * 256 + threadIdx.x;
    if (i < N) rowptr[i] = rowtmp[i] + boff[blockIdx.x];
    if (i == 0) rowptr[N] = Et;
}

__global__ __launch_bounds__(256) void scatter_k(
    const int* __restrict__ ei, const int* __restrict__ rowptr,
    int* __restrict__ cur, int* __restrict__ col, int E, int N)
{
    int e = blockIdx.x * 256 + threadIdx.x;
    int Et = E + N;
    if (e >= Et) return;
    int s, d;
    if (e < E) { s = ei[e]; d = ei[E + e]; } else { s = e - E; d = s; }
    int pos = atomicAdd(&cur[d], 1);
    col[rowptr[d] + pos] = s;
}

// ---------------------------------------------------------------------------
// Fused softmax + gather (r9). LPN = H*16 lanes/node, feature pair per lane.
// Phase 1: cache first LPN edges in regs + accumulate denominator.
// Phase 2: broadcast src/exp via wave-uniform shfl, coalesced h-row gather.
// No max-subtraction: logits O(4), exp safe.
// ---------------------------------------------------------------------------
template <int H>
__global__ __launch_bounds__(256) void node_sg_k(
    const int* __restrict__ rowptr, const int* __restrict__ col,
    const float* __restrict__ es, const float* __restrict__ ed,
    const unsigned short* __restrict__ hb, float* __restrict__ out, int N)
{
    constexpr int LPN = H * 16;            // 32 (H=2) or 16 (H=1)
    int t = blockIdx.x * 256 + threadIdx.x;
    int node = t / LPN;
    int lane = t - node * LPN;
    if (node >= N) return;
    int base = rowptr[node];
    int deg = rowptr[node + 1] - base;

    const uint* h2 = (const uint*)hb;      // row stride = LPN uints
    const float2* es2 = (const float2*)es;

    float ed0, ed1 = 0.f;
    if constexpr (H == 2) {
        float2 e = ((const float2*)ed)[node];
        ed0 = e.x; ed1 = e.y;
    } else {
        ed0 = ed[node];
    }

    // ---- phase 1: cache first LPN edges; accumulate denominator ----
    int sc_ = 0;
    float x0 = 0.f, x1 = 0.f;
    if (lane < deg) {
        sc_ = col[base + lane];
        if constexpr (H == 2) {
            float2 v = es2[sc_];
            x0 = __expf(lrelu(v.x + ed0));
            x1 = __expf(lrelu(v.y + ed1));
        } else {
            x0 = __expf(lrelu(es[sc_] + ed0));
        }
    }
    float s0 = x0, s1 = x1;
    for (int e = lane + LPN; e < deg; e += LPN) {
        int s = col[base + e];
        if constexpr (H == 2) {
            float2 v = es2[s];
            s0 += __expf(lrelu(v.x + ed0));
            s1 += __expf(lrelu(v.y + ed1));
        } else {
            s0 += __expf(lrelu(es[s] + ed0));
        }
    }
#pragma unroll
    for (int m = LPN / 2; m; m >>= 1) {
        s0 += __shfl_xor(s0, m, LPN);
        if (H == 2) s1 += __shfl_xor(s1, m, LPN);
    }
    float rd0 = 1.f / (s0 + 1e-16f);
    float rd1 = (H == 2) ? 1.f / (s1 + 1e-16f) : 0.f;

    // ---- phase 2: weighted gather ----
    const bool hi = (H == 2) && (lane >= 16);
    float acc0 = 0.f, acc1 = 0.f;
    int dcap = deg < LPN ? deg : LPN;
    int e = 0;
    for (; e + 4 <= dcap; e += 4) {
        int sI[4];
        float a[4];
#pragma unroll
        for (int u = 0; u < 4; ++u) {
            sI[u] = __shfl(sc_, e + u, LPN);
            float a0 = __shfl(x0, e + u, LPN);
            if constexpr (H == 2) {
                float a1 = __shfl(x1, e + u, LPN);
                a[u] = hi ? a1 * rd1 : a0 * rd0;
            } else {
                a[u] = a0 * rd0;
            }
        }
        uint v[4];
#pragma unroll
        for (int u = 0; u < 4; ++u) v[u] = h2[(size_t)sI[u] * LPN + lane];
#pragma unroll
        for (int u = 0; u < 4; ++u) {
            acc0 += a[u] * bf2f((unsigned short)v[u]);
            acc1 += a[u] * bf2f((unsigned short)(v[u] >> 16));
        }
    }
    for (; e < dcap; ++e) {
        int sI = __shfl(sc_, e, LPN);
        float a0 = __shfl(x0, e, LPN);
        float a;
        if constexpr (H == 2) {
            float a1 = __shfl(x1, e, LPN);
            a = hi ? a1 * rd1 : a0 * rd0;
        } else {
            a = a0 * rd0;
        }
        uint v = h2[(size_t)sI * LPN + lane];
        acc0 += a * bf2f((unsigned short)v);
        acc1 += a * bf2f((unsigned short)(v >> 16));
    }
    for (int e2 = LPN; e2 < deg; ++e2) {       // rare tail
        int s = col[base + e2];
        float a;
        if constexpr (H == 2) {
            float2 vv = es2[s];
            a = hi ? __expf(lrelu(vv.y + ed1)) * rd1
                   : __expf(lrelu(vv.x + ed0)) * rd0;
        } else {
            a = __expf(lrelu(es[s] + ed0)) * rd0;
        }
        uint v = h2[(size_t)s * LPN + lane];
        acc0 += a * bf2f((unsigned short)v);
        acc1 += a * bf2f((unsigned short)(v >> 16));
    }
    ((float2*)out)[(size_t)node * LPN + lane] = make_float2(acc0, acc1);
}

// ---------------------------------------------------------------------------
// BN: atomic-free two-stage stats, then scale/shift finalize.
// ---------------------------------------------------------------------------
template <int F>
__global__ __launch_bounds__(256) void bn_stats_k(
    const float* __restrict__ x, float* __restrict__ psum,
    float* __restrict__ psumsq, int N)
{
    constexpr int RG = 256 / F;
    int f = threadIdx.x & (F - 1);
    int r = threadIdx.x / F;
    float s = 0.f, s2 = 0.f;
    for (int n = blockIdx.x * RG + r; n < N; n += gridDim.x * RG) {
        float v = x[(size_t)n * F + f];
        s += v;
        s2 += v * v;
    }
    __shared__ float ls[256], ls2[256];
    ls[threadIdx.x] = s;
    ls2[threadIdx.x] = s2;
    __syncthreads();
    if (threadIdx.x < F) {
#pragma unroll
        for (int g = 1; g < RG; ++g) { s += ls[g * F + f]; s2 += ls2[g * F + f]; }
        psum[blockIdx.x * F + f] = s;
        psumsq[blockIdx.x * F + f] = s2;
    }
}

__global__ void bn_final_k(const float* __restrict__ psum,
                           const float* __restrict__ psumsq,
                           const float* __restrict__ gamma,
                           const float* __restrict__ beta,
                           float* __restrict__ scale, float* __restrict__ shift,
                           int N, int F, int NB)
{
    int f = threadIdx.x;
    if (f >= F) return;
    float s = 0.f, s2 = 0.f;
    for (int b = 0; b < NB; ++b) { s += psum[b * F + f]; s2 += psumsq[b * F + f]; }
    float inv = 1.f / (float)N;
    float mu = s * inv;
    float var = s2 * inv - mu * mu;
    var = fmaxf(var, 0.f);
    float rs = rsqrtf(var + 1e-5f);
    float sc = rs * gamma[f];
    scale[f] = sc;
    shift[f] = beta[f] - mu * sc;
}

__global__ __launch_bounds__(256) void out_final_k(
    const float* __restrict__ x, const float* __restrict__ scale,
    const float* __restrict__ shift, float* __restrict__ out, int total)
{
    int i = blockIdx.x * 256 + threadIdx.x;
    if (i >= total) return;
    int f = i & 31;
    out[i] = fmaxf(x[i] * scale[f] + shift[f], 0.f);
}

// ---------------------------------------------------------------------------

extern "C" void kernel_launch(void* const* d_in, const int* in_sizes, int n_in,
                              void* d_out, int out_size, void* d_ws,
                              size_t ws_size, hipStream_t stream)
{
    const float* x   = (const float*)d_in[0];
    const float* W1  = (const float*)d_in[1];
    const float* as1 = (const float*)d_in[2];
    const float* ad1 = (const float*)d_in[3];
    const float* g1  = (const float*)d_in[5];
    const float* be1 = (const float*)d_in[6];
    const float* W2  = (const float*)d_in[7];
    const float* as2 = (const float*)d_in[8];
    const float* ad2 = (const float*)d_in[9];
    const float* g2  = (const float*)d_in[11];
    const float* be2 = (const float*)d_in[12];
    const float* W3  = (const float*)d_in[13];
    const float* as3 = (const float*)d_in[14];
    const float* ad3 = (const float*)d_in[15];
    const float* g3  = (const float*)d_in[17];
    const float* be3 = (const float*)d_in[18];
    const int*   ei  = (const int*)d_in[19];

    const int N  = in_sizes[0] / 128;   // 50000
    const int E  = in_sizes[19] / 2;    // 800000
    const int Et = E + N;
    const int nb = (N + 255) / 256;
    const int NBN = 128;                // bn_stats blocks

    // Workspace layout (4-byte words).
    float* ws = (float*)d_ws;
    size_t off = 0;
    unsigned short* Hb = (unsigned short*)(ws + off); off += (size_t)N * 32; // bf16 [N,64]
    float* AGG = ws + off;  off += (size_t)N * 64;
    float* ES  = ws + off;  off += (size_t)N * 2;
    float* ED  = ws + off;  off += (size_t)N * 2;
    float* SC  = ws + off;  off += 64;
    float* SH  = ws + off;  off += 64;
    float* PS  = ws + off;  off += (size_t)NBN * 64;
    float* PS2 = ws + off;  off += (size_t)NBN * 64;
    int* deg    = (int*)(ws + off);  off += N;        // reused as scatter cursor
    int* rowtmp = (int*)(ws + off);  off += N;
    int* bsum   = (int*)(ws + off);  off += 256;
    int* boff   = (int*)(ws + off);  off += 256;
    int* rowptr = (int*)(ws + off);  off += (size_t)N + 1;
    int* col    = (int*)(ws + off);  off += (size_t)Et;

    const int tiles      = (N + 127) / 128;
    const int gemm2Blocks = tiles * 2;   // head-split for OUTF=64
    const int gemm1Blocks = tiles;       // OUTF=32
    const int sg64Blocks = (int)(((size_t)N * 32 + 255) / 256);  // LPN=32
    const int sg32Blocks = (int)(((size_t)N * 16 + 255) / 256);  // LPN=16
    const int edgeBlocks = (Et + 255) / 256;
    const int n32Blocks  = (N * 32 + 255) / 256;

    // ---------------- CSR build (once per call) ----------------
    hipMemsetAsync(deg, 0, (size_t)N * sizeof(int), stream);
    deg_k<<<edgeBlocks, 256, 0, stream>>>(ei, deg, E, N);
    scan1_k<<<nb, 256, 0, stream>>>(deg, rowtmp, bsum, N);
    scan2_k<<<1, 256, 0, stream>>>(bsum, boff, nb);
    scan3_k<<<nb, 256, 0, stream>>>(rowtmp, boff, rowptr, N, Et);
    hipMemsetAsync(deg, 0, (size_t)N * sizeof(int), stream);
    scatter_k<<<edgeBlocks, 256, 0, stream>>>(ei, rowptr, deg, col, E, N);

    // ---------------- Layer 1: 128 -> [2 x 32] ----------------
    gemm_attn_k<128, 64, 2, false><<<gemm2Blocks, 256, 0, stream>>>(
        x, W1, nullptr, nullptr, as1, ad1, Hb, ES, ED, N);
    node_sg_k<2><<<sg64Blocks, 256, 0, stream>>>(rowptr, col, ES, ED, Hb, AGG, N);
    bn_stats_k<64><<<NBN, 256, 0, stream>>>(AGG, PS, PS2, N);
    bn_final_k<<<1, 64, 0, stream>>>(PS, PS2, g1, be1, SC, SH, N, 64, NBN);

    // ---------------- Layer 2: 64 -> [2 x 32] ----------------
    gemm_attn_k<64, 64, 2, true><<<gemm2Blocks, 256, 0, stream>>>(
        AGG, W2, SC, SH, as2, ad2, Hb, ES, ED, N);
    node_sg_k<2><<<sg64Blocks, 256, 0, stream>>>(rowptr, col, ES, ED, Hb, AGG, N);
    bn_stats_k<64><<<NBN, 256, 0, stream>>>(AGG, PS, PS2, N);
    bn_final_k<<<1, 64, 0, stream>>>(PS, PS2, g2, be2, SC, SH, N, 64, NBN);

    // ---------------- Layer 3: 64 -> [1 x 32] ----------------
    gemm_attn_k<64, 32, 1, true><<<gemm1Blocks, 256, 0, stream>>>(
        AGG, W3, SC, SH, as3, ad3, Hb, ES, ED, N);
    node_sg_k<1><<<sg32Blocks, 256, 0, stream>>>(rowptr, col, ES, ED, Hb, AGG, N);
    bn_stats_k<32><<<NBN, 256, 0, stream>>>(AGG, PS, PS2, N);
    bn_final_k<<<1, 32, 0, stream>>>(PS, PS2, g3, be3, SC, SH, N, 32, NBN);
    out_final_k<<<n32Blocks, 256, 0, stream>>>(AGG, SC, SH, (float*)d_out, N * 32);
}